// Round 1
// baseline (227.401 us; speedup 1.0000x reference)
//
#include <hip/hip_runtime.h>

// Problem constants (reference: H = W = 2048, C = 8, N = 1e6)
#define HH 2048
#define WW 2048
#define CC 8
#define MODV 2044.0f   // H - 4

__device__ __forceinline__ float lerp3(float tl, float tr, float bl, float br,
                                       float d0, float d1) {
    // mid_bottom = br + d0*(bl - br); mid_top = tr + d0*(tl - tr)
    // out = mid_bottom + d1*(mid_top - mid_bottom)
    float mb = br + d0 * (bl - br);
    float mt = tr + d0 * (tl - tr);
    return mb + d1 * (mt - mb);
}

__global__ __launch_bounds__(256) void idx2pixel_kernel(
    const float* __restrict__ coords,   // (N, 2)
    const float* __restrict__ visible,  // (H, W, C) row-major
    float* __restrict__ out,            // (N, C)
    int n)
{
    int t = blockIdx.x * blockDim.x + threadIdx.x;
    if (t >= n) return;

    float2 co = *reinterpret_cast<const float2*>(coords + 2 * (size_t)t);

    // c = (coord - 1) mod 2044 + 1   (floored mod, positive divisor)
    float x = co.x - 1.0f;
    float y = co.y - 1.0f;
    float cx = fmodf(x, MODV); if (cx < 0.0f) cx += MODV;
    float cy = fmodf(y, MODV); if (cy < 0.0f) cy += MODV;
    cx += 1.0f;
    cy += 1.0f;

    float fx = floorf(cx);
    float fy = floorf(cy);
    float d0 = cx - fx;     // delta along dim 0 (rows)
    float d1 = cy - fy;     // delta along dim 1 (cols)
    int i0 = (int)fx;       // row index, in [1, 2044]
    int i1 = (int)fy;       // col index, in [1, 2044]

    // Reference naming (follow the code, not the names):
    //   top_left     = g(0,0) = V[i0  ][i1  ]
    //   top_right    = g(1,0) = V[i0+1][i1  ]
    //   bottom_left  = g(0,1) = V[i0  ][i1+1]
    //   bottom_right = g(1,1) = V[i0+1][i1+1]
    const float* p00 = visible + ((size_t)i0 * WW + (size_t)i1) * CC;
    const float* p01 = p00 + CC;               // col+1 (contiguous with p00)
    const float* p10 = p00 + (size_t)WW * CC;  // row+1
    const float* p11 = p10 + CC;

    float4 tl0 = *reinterpret_cast<const float4*>(p00);
    float4 tl1 = *reinterpret_cast<const float4*>(p00 + 4);
    float4 bl0 = *reinterpret_cast<const float4*>(p01);
    float4 bl1 = *reinterpret_cast<const float4*>(p01 + 4);
    float4 tr0 = *reinterpret_cast<const float4*>(p10);
    float4 tr1 = *reinterpret_cast<const float4*>(p10 + 4);
    float4 br0 = *reinterpret_cast<const float4*>(p11);
    float4 br1 = *reinterpret_cast<const float4*>(p11 + 4);

    // off = c > dims; cond = off[:,0] (unreachable since c < 2045, kept for fidelity)
    bool zero = cx > (float)HH;
    float m = zero ? 0.0f : 1.0f;

    float4 o0, o1;
    o0.x = m * lerp3(tl0.x, tr0.x, bl0.x, br0.x, d0, d1);
    o0.y = m * lerp3(tl0.y, tr0.y, bl0.y, br0.y, d0, d1);
    o0.z = m * lerp3(tl0.z, tr0.z, bl0.z, br0.z, d0, d1);
    o0.w = m * lerp3(tl0.w, tr0.w, bl0.w, br0.w, d0, d1);
    o1.x = m * lerp3(tl1.x, tr1.x, bl1.x, br1.x, d0, d1);
    o1.y = m * lerp3(tl1.y, tr1.y, bl1.y, br1.y, d0, d1);
    o1.z = m * lerp3(tl1.z, tr1.z, bl1.z, br1.z, d0, d1);
    o1.w = m * lerp3(tl1.w, tr1.w, bl1.w, br1.w, d0, d1);

    float* po = out + (size_t)t * CC;
    *reinterpret_cast<float4*>(po)     = o0;
    *reinterpret_cast<float4*>(po + 4) = o1;
}

extern "C" void kernel_launch(void* const* d_in, const int* in_sizes, int n_in,
                              void* d_out, int out_size, void* d_ws, size_t ws_size,
                              hipStream_t stream) {
    const float* coords  = (const float*)d_in[0];  // (N, 2) fp32
    const float* visible = (const float*)d_in[1];  // (2048, 2048, 8) fp32
    float* out = (float*)d_out;                    // (N, 8) fp32
    int n = in_sizes[0] / 2;

    int block = 256;
    int grid = (n + block - 1) / block;
    idx2pixel_kernel<<<grid, block, 0, stream>>>(coords, visible, out, n);
}